// Round 11
// baseline (113.482 us; speedup 1.0000x reference)
//
#include <hip/hip_runtime.h>
#include <cstddef>

// Problem constants
#define P_TOTAL 32768            // keys (32 images x 32 x 32)
#define Q_TOTAL 4096             // queries (4 x 32 x 32)
#define NSPLIT 256               // key splits
#define KPS 128                  // keys per split
#define NGROUP 4                 // 32-key (tile-pair) groups per split
#define QPERWG 256               // queries per workgroup (4 waves x 64)
#define NQG (Q_TOTAL / QPERWG)   // 16 query groups
#define GRID (NSPLIT * NQG)      // 4096 workgroups

// LDS layout (bytes)
#define KEYS_B (KPS * 64)        // 8192
#define VT_OFF KEYS_B
#define VT_PITCH 272             // 128 halves + pad
#define LDS_TOTAL (VT_OFF + 4 * VT_PITCH)   // 9280 B

typedef _Float16 half8 __attribute__((ext_vector_type(8)));
typedef __fp16 fp16x2 __attribute__((ext_vector_type(2)));
typedef __fp16 fp16x4 __attribute__((ext_vector_type(4)));
typedef __fp16 fp16x8 __attribute__((ext_vector_type(8)));
typedef float floatx4 __attribute__((ext_vector_type(4)));

union h8cast { fp16x8 a; half8 b; };

__device__ __forceinline__ float fexp2(float x) {
#if defined(__has_builtin) && __has_builtin(__builtin_amdgcn_exp2f)
    return __builtin_amdgcn_exp2f(x);
#else
    return exp2f(x);
#endif
}

// ---------------------------------------------------------------------------
// Kernel 1: q16[Q][32] f16 query rows (27 patch vals, 1.0 bias-mate, zeros).
// ---------------------------------------------------------------------------
__global__ __launch_bounds__(256) void qbuild_k(
    const float* __restrict__ x, _Float16* __restrict__ q16)
{
    int q = blockIdx.x * 256 + threadIdx.x;   // 0..4095
    int b = q >> 10, rem = q & 1023, h = rem >> 5, w = rem & 31;
    const float* xb = x + (size_t)b * 3072;
    _Float16 row[32];
    #pragma unroll
    for (int c = 0; c < 3; c++)
      #pragma unroll
      for (int di = 0; di < 3; di++)
        #pragma unroll
        for (int dj = 0; dj < 3; dj++)
            row[c * 9 + di * 3 + dj] =
                (_Float16)xb[c * 1024 + ((h + di + 31) & 31) * 32 + ((w + dj + 31) & 31)];
    row[27] = (_Float16)1.0f;
    row[28] = (_Float16)0.f; row[29] = (_Float16)0.f;
    row[30] = (_Float16)0.f; row[31] = (_Float16)0.f;
    _Float16* qp = q16 + (size_t)q * 32;
    #pragma unroll
    for (int u = 0; u < 4; u++) ((float4*)qp)[u] = ((float4*)row)[u];
}

// ---------------------------------------------------------------------------
// Kernel 2: fused key-build + SINGLE-PASS online flash scorer, zero-copy P.
// Key row permutation at build time (R10-verified): QK D output, after
// exp2+pkrtz, IS the PV B-operand over a tile pair — no LDS round-trip.
// Per 32-key group: QK (C=0) -> 8-wide max -> 2 cross-quad shuffles ->
// online m update -> acc rescale (4 mul) -> exp2(a-m) -> pkrtz -> PV MFMA
// (A = V^T rows [1,c0,c1,c2], kk-ordered; cols>=4 register zeros).
// QK MFMAs are independent across groups (m subtracted in VALU, not folded
// into C) so only the thin m/acc chain serializes. One QK pass total:
// MFMA/key -40%, LDS/key -40% vs R10. NSPLIT=256 -> 4096 wgs (~3 shifts).
// ---------------------------------------------------------------------------
__global__ __launch_bounds__(256) void score_k(
    const _Float16* __restrict__ q16, const float* __restrict__ images,
    const float* __restrict__ mu_sched, const float* __restrict__ sigma_sched,
    const int* __restrict__ tptr, float* __restrict__ partials)
{
    __shared__ char lds[LDS_TOTAL];
    int tid = threadIdx.x;
    int split = blockIdx.x >> 4;     // 0..255
    int qg    = blockIdx.x & 15;     // 0..15

    int t = tptr[0];
    float mu = mu_sched[t], sg = sigma_sched[t];
    const float LOG2E = 1.4426950408889634f;
    float inv2s2 = 1.0f / (2.0f * sg * sg);
    float s1     = 2.0f * mu * inv2s2 * LOG2E;   // key value scale
    float bscale = -mu * mu * inv2s2 * LOG2E;    // pnorm bias scale

    // ---- Phase 1: build this split's 128 keys into LDS (threads 0..127) ----
    if (tid < KPS) {
        int r = tid;                             // LDS key row 0..127
        int m16 = r & 15, tt = (r >> 4) & 1, tp = r >> 5;
        int kk = tp * 32 + (m16 >> 2) * 8 + tt * 4 + (m16 & 3);  // in-split key
        int p = split * KPS + kk;
        int n = p >> 10, rem = p & 1023, i = rem >> 5, j = rem & 31;
        const float* img = images + (size_t)n * 3072;
        _Float16 hrow[32];
        float pnorm = 0.f, c0 = 0.f, c1 = 0.f, c2 = 0.f;
        #pragma unroll
        for (int c = 0; c < 3; c++)
          #pragma unroll
          for (int di = 0; di < 3; di++)
            #pragma unroll
            for (int dj = 0; dj < 3; dj++) {
                int ii = i + di - 1, jj = j + dj - 1;
                float val = 0.f;
                if (ii >= 0 && ii < 32 && jj >= 0 && jj < 32)
                    val = img[c * 1024 + ii * 32 + jj];
                hrow[c * 9 + di * 3 + dj] = (_Float16)(val * s1);
                pnorm = fmaf(val, val, pnorm);
                if (di == 1 && dj == 1) { if (c == 0) c0 = val; else if (c == 1) c1 = val; else c2 = val; }
            }
        hrow[27] = (_Float16)(pnorm * bscale);
        hrow[28] = (_Float16)0.f; hrow[29] = (_Float16)0.f;
        hrow[30] = (_Float16)0.f; hrow[31] = (_Float16)0.f;
        int sw = (r >> 1) & 3;                   // 16B-chunk XOR swizzle
        float4* src4 = (float4*)hrow;
        #pragma unroll
        for (int c = 0; c < 4; c++)
            *(float4*)(lds + r * 64 + ((c ^ sw) << 4)) = src4[c];
        // VT rows (kk-indexed): [1, c0, c1, c2]
        _Float16* vt = (_Float16*)(lds + VT_OFF);
        vt[0 * (VT_PITCH / 2) + kk] = (_Float16)1.0f;
        vt[1 * (VT_PITCH / 2) + kk] = (_Float16)c0;
        vt[2 * (VT_PITCH / 2) + kk] = (_Float16)c1;
        vt[3 * (VT_PITCH / 2) + kk] = (_Float16)c2;
    }

    // ---- B-fragments: queries from q16 (global, L2-hot) ----
    int lane = tid & 63, wid = tid >> 6;
    int col  = lane & 15, quad = lane >> 4;
    int qbase = qg * QPERWG + wid * 64;

    half8 qf[4];
    #pragma unroll
    for (int f = 0; f < 4; f++)
        qf[f] = *(const half8*)(q16 + (size_t)(qbase + f * 16 + col) * 32 + quad * 8);
    __syncthreads();

    int swc = (col >> 1) & 3;
    const char* abase = lds + col * 64 + ((quad ^ swc) << 4);
    const char* vrow  = lds + VT_OFF + col * VT_PITCH;     // valid for col<4

    float mrun[4] = {-3e38f, -3e38f, -3e38f, -3e38f};
    floatx4 acc[4];
    #pragma unroll
    for (int f = 0; f < 4; f++) acc[f] = (floatx4){0.f, 0.f, 0.f, 0.f};

    #pragma unroll
    for (int g = 0; g < NGROUP; g++) {
        half8 ak0 = *(const half8*)(abase + (2 * g) * 1024);
        half8 ak1 = *(const half8*)(abase + (2 * g + 1) * 1024);
        half8 av = (half8)(_Float16)0.f;
        if (col < 4) av = *(const half8*)(vrow + g * 64 + quad * 16);
        #pragma unroll
        for (int f = 0; f < 4; f++) {
            floatx4 a0 = __builtin_amdgcn_mfma_f32_16x16x32_f16(
                ak0, qf[f], (floatx4){0.f, 0.f, 0.f, 0.f}, 0, 0, 0);
            floatx4 a1 = __builtin_amdgcn_mfma_f32_16x16x32_f16(
                ak1, qf[f], (floatx4){0.f, 0.f, 0.f, 0.f}, 0, 0, 0);
            // group max over this lane's 8 logits, then cross-quad
            float L = fmaxf(fmaxf(fmaxf(a0[0], a0[1]), fmaxf(a0[2], a0[3])),
                            fmaxf(fmaxf(a1[0], a1[1]), fmaxf(a1[2], a1[3])));
            L = fmaxf(L, __shfl_xor(L, 16, 64));
            L = fmaxf(L, __shfl_xor(L, 32, 64));
            float mnew = fmaxf(mrun[f], L);
            float scale = fexp2(mrun[f] - mnew);   // 0 on first group
            mrun[f] = mnew;
            acc[f] *= scale;
            fp16x2 p00 = __builtin_amdgcn_cvt_pkrtz(fexp2(a0[0] - mnew), fexp2(a0[1] - mnew));
            fp16x2 p01 = __builtin_amdgcn_cvt_pkrtz(fexp2(a0[2] - mnew), fexp2(a0[3] - mnew));
            fp16x2 p10 = __builtin_amdgcn_cvt_pkrtz(fexp2(a1[0] - mnew), fexp2(a1[1] - mnew));
            fp16x2 p11 = __builtin_amdgcn_cvt_pkrtz(fexp2(a1[2] - mnew), fexp2(a1[3] - mnew));
            fp16x4 lo = __builtin_shufflevector(p00, p01, 0, 1, 2, 3);
            fp16x4 hi = __builtin_shufflevector(p10, p11, 0, 1, 2, 3);
            h8cast u; u.a = __builtin_shufflevector(lo, hi, 0, 1, 2, 3, 4, 5, 6, 7);
            acc[f] = __builtin_amdgcn_mfma_f32_16x16x32_f16(av, u.b, acc[f], 0, 0, 0);
        }
    }

    // ---- store: quad-0 lane holds comps [sum,w0,w1,w2] for query f*16+col ----
    if (quad == 0) {
        const size_t PL = (size_t)NSPLIT * Q_TOTAL;
        #pragma unroll
        for (int f = 0; f < 4; f++) {
            size_t idx = (size_t)split * Q_TOTAL + qbase + f * 16 + col;
            partials[idx]          = mrun[f];
            partials[idx + PL]     = acc[f][0];
            partials[idx + PL * 2] = acc[f][1];
            partials[idx + PL * 3] = acc[f][2];
            partials[idx + PL * 4] = acc[f][3];
        }
    }
}

// ---------------------------------------------------------------------------
// Kernel 3: merge NSPLIT partials per query.  64 wgs; wave w of a wg handles
// splits w*64..+63 for 64 consecutive queries (coalesced loads); 4 chains
// merged through LDS; wave 0 writes output.
// ---------------------------------------------------------------------------
__global__ __launch_bounds__(256) void combine_k(
    const float* __restrict__ x, const float* __restrict__ partials,
    const float* __restrict__ mu_sched, const float* __restrict__ sigma_sched,
    const int* __restrict__ tptr, float* __restrict__ out)
{
    __shared__ float red[5][4][64];
    int tid = threadIdx.x;
    int wid = tid >> 6, lane = tid & 63;
    int q = blockIdx.x * 64 + lane;
    int t = tptr[0];
    float mu = mu_sched[t], sg = sigma_sched[t];
    float inv_s2 = 1.0f / (sg * sg);

    const size_t PL = (size_t)NSPLIT * Q_TOTAL;
    float M = -3e38f, S = 0.f, W0 = 0.f, W1 = 0.f, W2 = 0.f;
    int sp0 = wid * (NSPLIT / 4);
    #pragma unroll 4
    for (int i = 0; i < NSPLIT / 4; i++) {
        size_t idx = (size_t)(sp0 + i) * Q_TOTAL + q;
        float mval = partials[idx];
        float mnew = fmaxf(M, mval);
        float sco = fexp2(M - mnew), scn = fexp2(mval - mnew);
        S  = fmaf(S,  sco, partials[idx + PL] * scn);
        W0 = fmaf(W0, sco, partials[idx + PL * 2] * scn);
        W1 = fmaf(W1, sco, partials[idx + PL * 3] * scn);
        W2 = fmaf(W2, sco, partials[idx + PL * 4] * scn);
        M = mnew;
    }
    red[0][wid][lane] = M;  red[1][wid][lane] = S;
    red[2][wid][lane] = W0; red[3][wid][lane] = W1; red[4][wid][lane] = W2;
    __syncthreads();

    if (wid == 0) {
        float Mf = red[0][0][lane];
        #pragma unroll
        for (int wv = 1; wv < 4; wv++) Mf = fmaxf(Mf, red[0][wv][lane]);
        float Sf = 0.f, A = 0.f, B = 0.f, C = 0.f;
        #pragma unroll
        for (int wv = 0; wv < 4; wv++) {
            float r = fexp2(red[0][wv][lane] - Mf);
            Sf = fmaf(red[1][wv][lane], r, Sf);
            A  = fmaf(red[2][wv][lane], r, A);
            B  = fmaf(red[3][wv][lane], r, B);
            C  = fmaf(red[4][wv][lane], r, C);
        }
        float invS = 1.0f / Sf;
        int b = q >> 10, rem = q & 1023;
        #pragma unroll
        for (int c = 0; c < 3; c++) {
            float Wc = (c == 0) ? A : (c == 1 ? B : C);
            float xc = x[(size_t)b * 3072 + c * 1024 + rem];
            out[(size_t)b * 3072 + c * 1024 + rem] = -(xc - mu * Wc * invS) * inv_s2;
        }
    }
}

extern "C" void kernel_launch(void* const* d_in, const int* in_sizes, int n_in,
                              void* d_out, int out_size, void* d_ws, size_t ws_size,
                              hipStream_t stream) {
    const float* x      = (const float*)d_in[0];
    const float* images = (const float*)d_in[1];
    const float* mu_s   = (const float*)d_in[2];
    const float* sg_s   = (const float*)d_in[3];
    const int*   tptr   = (const int*)d_in[4];
    float* out = (float*)d_out;

    float*    partials = (float*)d_ws;   // 5 planes x 256 x 4096 x 4 B = 21 MB
    _Float16* q16      = (_Float16*)((char*)d_ws + (size_t)5 * NSPLIT * Q_TOTAL * 4);

    qbuild_k<<<Q_TOTAL / 256, 256, 0, stream>>>(x, q16);
    score_k<<<GRID, 256, 0, stream>>>(q16, images, mu_s, sg_s, tptr, partials);
    combine_k<<<Q_TOTAL / 64, 256, 0, stream>>>(
        x, partials, mu_s, sg_s, tptr, out);
}

// Round 12
// 100.248 us; speedup vs baseline: 1.1320x; 1.1320x over previous
//
#include <hip/hip_runtime.h>
#include <cstddef>

// Problem constants
#define P_TOTAL 32768            // keys (32 images x 32 x 32)
#define Q_TOTAL 4096             // queries (4 x 32 x 32)
#define NSPLIT 128               // key splits
#define KPS 256                  // keys per split
#define TILES 16                 // 16-key MFMA tiles per split
#define NGROUP 8                 // 32-key (tile-pair) PV groups per split
#define QPERWG 256               // queries per workgroup (4 waves x 64)
#define NQG (Q_TOTAL / QPERWG)   // 16 query groups
#define GRID (NSPLIT * NQG)      // 2048 workgroups

// LDS layout (bytes)
#define KEYS_B 16384             // 256 rows x 64 B
#define VT_OFF KEYS_B            // V^T: 4 rows x 528 B (kk-ordered)
#define VT_PITCH 528
#define LDS_TOTAL (VT_OFF + 4 * VT_PITCH)   // 18496 B

typedef _Float16 half8 __attribute__((ext_vector_type(8)));
typedef __fp16 fp16x2 __attribute__((ext_vector_type(2)));
typedef __fp16 fp16x4 __attribute__((ext_vector_type(4)));
typedef __fp16 fp16x8 __attribute__((ext_vector_type(8)));
typedef float floatx4 __attribute__((ext_vector_type(4)));

union h8cast { fp16x8 a; half8 b; };

__device__ __forceinline__ float fexp2(float x) {
#if defined(__has_builtin) && __has_builtin(__builtin_amdgcn_exp2f)
    return __builtin_amdgcn_exp2f(x);
#else
    return exp2f(x);
#endif
}

// ---------------------------------------------------------------------------
// Kernel 1: q16[Q][32] f16 query rows (27 patch vals, 1.0 bias-mate, zeros).
// ---------------------------------------------------------------------------
__global__ __launch_bounds__(256) void qbuild_k(
    const float* __restrict__ x, _Float16* __restrict__ q16)
{
    int q = blockIdx.x * 256 + threadIdx.x;   // 0..4095
    int b = q >> 10, rem = q & 1023, h = rem >> 5, w = rem & 31;
    const float* xb = x + (size_t)b * 3072;
    _Float16 row[32];
    #pragma unroll
    for (int c = 0; c < 3; c++)
      #pragma unroll
      for (int di = 0; di < 3; di++)
        #pragma unroll
        for (int dj = 0; dj < 3; dj++)
            row[c * 9 + di * 3 + dj] =
                (_Float16)xb[c * 1024 + ((h + di + 31) & 31) * 32 + ((w + dj + 31) & 31)];
    row[27] = (_Float16)1.0f;
    row[28] = (_Float16)0.f; row[29] = (_Float16)0.f;
    row[30] = (_Float16)0.f; row[31] = (_Float16)0.f;
    _Float16* qp = q16 + (size_t)q * 32;
    #pragma unroll
    for (int u = 0; u < 4; u++) ((float4*)qp)[u] = ((float4*)row)[u];
}

// ---------------------------------------------------------------------------
// Kernel 2 (R10 structure — best measured): fused key-build + two-pass
// flash scorer, zero-copy P path.  Key rows permuted at build time so the
// QK D output, after exp2+pkrtz, IS the PV B-operand over a tile pair.
// Pass 1: per-lane max (C=0 MFMAs, no cross-iteration deps).
// Pass 2: -m folded into QK C operand; PV MFMA accumulates [sum,w0,w1,w2].
// Two-pass beats single-pass online here (R11: +12 µs): no serial
// max/rescale chain through MFMA results.
// ---------------------------------------------------------------------------
__global__ __launch_bounds__(256) void score_k(
    const _Float16* __restrict__ q16, const float* __restrict__ images,
    const float* __restrict__ mu_sched, const float* __restrict__ sigma_sched,
    const int* __restrict__ tptr, float* __restrict__ partials)
{
    __shared__ char lds[LDS_TOTAL];
    int tid = threadIdx.x;
    int split = blockIdx.x >> 4;     // 0..127
    int qg    = blockIdx.x & 15;     // 0..15

    int t = tptr[0];
    float mu = mu_sched[t], sg = sigma_sched[t];
    const float LOG2E = 1.4426950408889634f;
    float inv2s2 = 1.0f / (2.0f * sg * sg);
    float s1     = 2.0f * mu * inv2s2 * LOG2E;   // key value scale
    float bscale = -mu * mu * inv2s2 * LOG2E;    // pnorm bias scale

    // ---- Phase 1: build 256 keys into LDS (permuted rows) + VT table ----
    {
        int r = tid;                             // LDS key row 0..255
        int m16 = r & 15, tt = (r >> 4) & 1, tp = r >> 5;
        int kk = tp * 32 + (m16 >> 2) * 8 + tt * 4 + (m16 & 3);  // in-split key
        int p = split * KPS + kk;
        int n = p >> 10, rem = p & 1023, i = rem >> 5, j = rem & 31;
        const float* img = images + (size_t)n * 3072;
        _Float16 hrow[32];
        float pnorm = 0.f, c0 = 0.f, c1 = 0.f, c2 = 0.f;
        #pragma unroll
        for (int c = 0; c < 3; c++)
          #pragma unroll
          for (int di = 0; di < 3; di++)
            #pragma unroll
            for (int dj = 0; dj < 3; dj++) {
                int ii = i + di - 1, jj = j + dj - 1;
                float val = 0.f;
                if (ii >= 0 && ii < 32 && jj >= 0 && jj < 32)
                    val = img[c * 1024 + ii * 32 + jj];
                hrow[c * 9 + di * 3 + dj] = (_Float16)(val * s1);
                pnorm = fmaf(val, val, pnorm);
                if (di == 1 && dj == 1) { if (c == 0) c0 = val; else if (c == 1) c1 = val; else c2 = val; }
            }
        hrow[27] = (_Float16)(pnorm * bscale);
        hrow[28] = (_Float16)0.f; hrow[29] = (_Float16)0.f;
        hrow[30] = (_Float16)0.f; hrow[31] = (_Float16)0.f;
        int sw = (r >> 1) & 3;                   // 16B-chunk XOR swizzle
        float4* src4 = (float4*)hrow;
        #pragma unroll
        for (int c = 0; c < 4; c++)
            *(float4*)(lds + r * 64 + ((c ^ sw) << 4)) = src4[c];
        // VT rows (kk-indexed): [1, c0, c1, c2]
        _Float16* vt = (_Float16*)(lds + VT_OFF);
        vt[0 * (VT_PITCH / 2) + kk] = (_Float16)1.0f;
        vt[1 * (VT_PITCH / 2) + kk] = (_Float16)c0;
        vt[2 * (VT_PITCH / 2) + kk] = (_Float16)c1;
        vt[3 * (VT_PITCH / 2) + kk] = (_Float16)c2;
    }

    // ---- B-fragments: queries from q16 (global, L2-hot) ----
    int lane = tid & 63, wid = tid >> 6;
    int col  = lane & 15, quad = lane >> 4;
    int qbase = qg * QPERWG + wid * 64;

    half8 qf[4];
    #pragma unroll
    for (int f = 0; f < 4; f++)
        qf[f] = *(const half8*)(q16 + (size_t)(qbase + f * 16 + col) * 32 + quad * 8);
    __syncthreads();

    int swc = (col >> 1) & 3;
    const char* abase = lds + col * 64 + ((quad ^ swc) << 4);   // QK A tile reads

    // ---- Pass 1: per-lane max over this lane's keys ----
    float mx[4];
    {
        floatx4 mv[4];
        #pragma unroll
        for (int f = 0; f < 4; f++) mv[f] = (floatx4){-3e38f, -3e38f, -3e38f, -3e38f};
        #pragma unroll 4
        for (int tile = 0; tile < TILES; tile++) {
            half8 ak = *(const half8*)(abase + tile * 1024);
            #pragma unroll
            for (int f = 0; f < 4; f++) {
                floatx4 a = __builtin_amdgcn_mfma_f32_16x16x32_f16(
                    ak, qf[f], (floatx4){0.f, 0.f, 0.f, 0.f}, 0, 0, 0);
                mv[f] = __builtin_elementwise_max(mv[f], a);
            }
        }
        #pragma unroll
        for (int f = 0; f < 4; f++) {
            mx[f] = fmaxf(fmaxf(mv[f][0], mv[f][1]), fmaxf(mv[f][2], mv[f][3]));
            mx[f] = fmaxf(mx[f], __shfl_xor(mx[f], 16, 64));
            mx[f] = fmaxf(mx[f], __shfl_xor(mx[f], 32, 64));
        }
    }
    floatx4 nmv[4];
    #pragma unroll
    for (int f = 0; f < 4; f++)
        nmv[f] = (floatx4){-mx[f], -mx[f], -mx[f], -mx[f]};

    // write m-plane (quad-0 lanes own query f*16+col)
    if (quad == 0) {
        #pragma unroll
        for (int f = 0; f < 4; f++)
            partials[(size_t)split * Q_TOTAL + qbase + f * 16 + col] = mx[f];
    }

    // ---- Pass 2: QK (-m in C) -> exp2 -> pkrtz -> PV MFMA, no LDS hop ----
    const char* vrow = lds + VT_OFF + col * VT_PITCH;   // valid for col<4
    floatx4 acc[4];
    #pragma unroll
    for (int f = 0; f < 4; f++) acc[f] = (floatx4){0.f, 0.f, 0.f, 0.f};

    #pragma unroll 2
    for (int g = 0; g < NGROUP; g++) {
        half8 ak0 = *(const half8*)(abase + (2 * g) * 1024);
        half8 ak1 = *(const half8*)(abase + (2 * g + 1) * 1024);
        // A operand = V^T fragment: lane(col,quad) = VT[col][g*32 + quad*8 .. +7]
        half8 av = (half8)(_Float16)0.f;
        if (col < 4) av = *(const half8*)(vrow + g * 64 + quad * 16);
        #pragma unroll
        for (int f = 0; f < 4; f++) {
            floatx4 a0 = __builtin_amdgcn_mfma_f32_16x16x32_f16(ak0, qf[f], nmv[f], 0, 0, 0);
            floatx4 a1 = __builtin_amdgcn_mfma_f32_16x16x32_f16(ak1, qf[f], nmv[f], 0, 0, 0);
            fp16x2 p00 = __builtin_amdgcn_cvt_pkrtz(fexp2(a0[0]), fexp2(a0[1]));
            fp16x2 p01 = __builtin_amdgcn_cvt_pkrtz(fexp2(a0[2]), fexp2(a0[3]));
            fp16x2 p10 = __builtin_amdgcn_cvt_pkrtz(fexp2(a1[0]), fexp2(a1[1]));
            fp16x2 p11 = __builtin_amdgcn_cvt_pkrtz(fexp2(a1[2]), fexp2(a1[3]));
            fp16x4 lo = __builtin_shufflevector(p00, p01, 0, 1, 2, 3);
            fp16x4 hi = __builtin_shufflevector(p10, p11, 0, 1, 2, 3);
            h8cast u; u.a = __builtin_shufflevector(lo, hi, 0, 1, 2, 3, 4, 5, 6, 7);
            acc[f] = __builtin_amdgcn_mfma_f32_16x16x32_f16(av, u.b, acc[f], 0, 0, 0);
        }
    }

    // ---- store: quad-0 lane holds comps [sum,w0,w1,w2] for query f*16+col ----
    if (quad == 0) {
        const size_t PL = (size_t)NSPLIT * Q_TOTAL;
        #pragma unroll
        for (int f = 0; f < 4; f++) {
            size_t idx = (size_t)split * Q_TOTAL + qbase + f * 16 + col;
            partials[idx + PL]     = acc[f][0];
            partials[idx + PL * 2] = acc[f][1];
            partials[idx + PL * 3] = acc[f][2];
            partials[idx + PL * 4] = acc[f][3];
        }
    }
}

// ---------------------------------------------------------------------------
// Kernel 3: merge NSPLIT partials per query.  64 wgs; wave w handles splits
// w*32..+31 for 64 consecutive queries (coalesced); 4 chains merged through
// LDS; wave 0 writes output.
// ---------------------------------------------------------------------------
__global__ __launch_bounds__(256) void combine_k(
    const float* __restrict__ x, const float* __restrict__ partials,
    const float* __restrict__ mu_sched, const float* __restrict__ sigma_sched,
    const int* __restrict__ tptr, float* __restrict__ out)
{
    __shared__ float red[5][4][64];
    int tid = threadIdx.x;
    int wid = tid >> 6, lane = tid & 63;
    int q = blockIdx.x * 64 + lane;
    int t = tptr[0];
    float mu = mu_sched[t], sg = sigma_sched[t];
    float inv_s2 = 1.0f / (sg * sg);

    const size_t PL = (size_t)NSPLIT * Q_TOTAL;
    float M = -3e38f, S = 0.f, W0 = 0.f, W1 = 0.f, W2 = 0.f;
    int sp0 = wid * (NSPLIT / 4);
    #pragma unroll 4
    for (int i = 0; i < NSPLIT / 4; i++) {
        size_t idx = (size_t)(sp0 + i) * Q_TOTAL + q;
        float mval = partials[idx];
        float mnew = fmaxf(M, mval);
        float sco = fexp2(M - mnew), scn = fexp2(mval - mnew);
        S  = fmaf(S,  sco, partials[idx + PL] * scn);
        W0 = fmaf(W0, sco, partials[idx + PL * 2] * scn);
        W1 = fmaf(W1, sco, partials[idx + PL * 3] * scn);
        W2 = fmaf(W2, sco, partials[idx + PL * 4] * scn);
        M = mnew;
    }
    red[0][wid][lane] = M;  red[1][wid][lane] = S;
    red[2][wid][lane] = W0; red[3][wid][lane] = W1; red[4][wid][lane] = W2;
    __syncthreads();

    if (wid == 0) {
        float Mf = red[0][0][lane];
        #pragma unroll
        for (int wv = 1; wv < 4; wv++) Mf = fmaxf(Mf, red[0][wv][lane]);
        float Sf = 0.f, A = 0.f, B = 0.f, C = 0.f;
        #pragma unroll
        for (int wv = 0; wv < 4; wv++) {
            float r = fexp2(red[0][wv][lane] - Mf);
            Sf = fmaf(red[1][wv][lane], r, Sf);
            A  = fmaf(red[2][wv][lane], r, A);
            B  = fmaf(red[3][wv][lane], r, B);
            C  = fmaf(red[4][wv][lane], r, C);
        }
        float invS = 1.0f / Sf;
        int b = q >> 10, rem = q & 1023;
        #pragma unroll
        for (int c = 0; c < 3; c++) {
            float Wc = (c == 0) ? A : (c == 1 ? B : C);
            float xc = x[(size_t)b * 3072 + c * 1024 + rem];
            out[(size_t)b * 3072 + c * 1024 + rem] = -(xc - mu * Wc * invS) * inv_s2;
        }
    }
}

extern "C" void kernel_launch(void* const* d_in, const int* in_sizes, int n_in,
                              void* d_out, int out_size, void* d_ws, size_t ws_size,
                              hipStream_t stream) {
    const float* x      = (const float*)d_in[0];
    const float* images = (const float*)d_in[1];
    const float* mu_s   = (const float*)d_in[2];
    const float* sg_s   = (const float*)d_in[3];
    const int*   tptr   = (const int*)d_in[4];
    float* out = (float*)d_out;

    float*    partials = (float*)d_ws;   // 5 planes x 128 x 4096 x 4 B = 10.5 MB
    _Float16* q16      = (_Float16*)((char*)d_ws + (size_t)5 * NSPLIT * Q_TOTAL * 4);

    qbuild_k<<<Q_TOTAL / 256, 256, 0, stream>>>(x, q16);
    score_k<<<GRID, 256, 0, stream>>>(q16, images, mu_s, sg_s, tptr, partials);
    combine_k<<<Q_TOTAL / 64, 256, 0, stream>>>(
        x, partials, mu_s, sg_s, tptr, out);
}